// Round 2
// baseline (211.644 us; speedup 1.0000x reference)
//
#include <hip/hip_runtime.h>

// YOLO-v1-style loss, exact port of the JAX reference.
// S=7, B=2, C=20, channels per cell = 30:
//   ch 0..19  : class scores
//   ch 20..24 : box0 x,y,w,h,conf
//   ch 25..29 : box1 x,y,w,h,conf
// cls part of the loss uses channels [5*B: i.e. 10..29] (reference quirk, kept).
//
// R5: double-buffered pipelined staging (T3-minimum 2-phase template).
// R4 (stage p -> drain -> read -> barrier -> stage a -> drain -> read) ran at
// the SAME 73 us as R3's uncoalesced direct loads: the drains serialize
// transfer and compute, memory pipe idles between bursts (16% HBM, 12% VALU).
// Now: grid-stride persistent blocks, tile=128 cells, BOTH tensors staged per
// tile (30,720 B/buffer), two buffers (61,440 B LDS -> 2 blocks/CU). Per tile:
//   STAGE(buf^1, t+1)  ->  ds_read+compute(buf)  ->  __syncthreads (vmcnt0)
// The drain waits on NEXT tile's loads, issued one full compute phase earlier;
// 2 resident blocks alternate so the CU always has loads in flight.

#define CH      30
#define EPSL    1e-6f
#define TPB     128
#define TILE_F  (TPB * CH)      // 3840 floats per tensor region (15,360 B)
#define TILE_F4 (TILE_F / 4)    // 960 float4s
#define BUF_F   (2 * TILE_F)    // 7680 floats per buffer (p region then a region)
#define GRID    512             // 2 blocks/CU on 256 CUs

typedef const __attribute__((address_space(1))) void* gas_ptr;
typedef __attribute__((address_space(3))) void* las_ptr;

__device__ __forceinline__ float sgnf(float x) {
    return (x > 0.0f) ? 1.0f : ((x < 0.0f) ? -1.0f : 0.0f);
}

// Stage one tile (both tensors) into buf: coalesced global->LDS, width=16.
__device__ __forceinline__ void stage_tile(const float* __restrict__ p,
                                           const float* __restrict__ a,
                                           float* buf, long long tile,
                                           int wid, int lane) {
    const float* gp = p + tile * (long long)TILE_F;
    const float* ga = a + tile * (long long)TILE_F;
#pragma unroll
    for (int k = 0; k < 8; ++k) {
        const int b4 = k * TPB + wid * 64;   // wave-uniform float4 base
        if (b4 < TILE_F4) {                  // wave-uniform guard
            __builtin_amdgcn_global_load_lds(
                (gas_ptr)(gp + (size_t)(b4 + lane) * 4),
                (las_ptr)(buf + (size_t)b4 * 4), 16, 0, 0);
        }
    }
#pragma unroll
    for (int k = 0; k < 8; ++k) {
        const int b4 = k * TPB + wid * 64;
        if (b4 < TILE_F4) {
            __builtin_amdgcn_global_load_lds(
                (gas_ptr)(ga + (size_t)(b4 + lane) * 4),
                (las_ptr)(buf + TILE_F + (size_t)b4 * 4), 16, 0, 0);
        }
    }
}

// Per-cell loss from channels 10..29 of p (pd) and a (ad).
__device__ __forceinline__ float cell_loss(const float* pd, const float* ad) {
    float lsum = 0.0f;

    // box attrs: channel 20+5b+i -> index 10+5b+i
    float pxv[2], pyv[2], pwv[2], phv[2], pcv[2];
    float axv[2], ayv[2], awv[2], ahv[2];
#pragma unroll
    for (int b = 0; b < 2; ++b) {
        pxv[b] = pd[10 + 5 * b]; pyv[b] = pd[11 + 5 * b];
        pwv[b] = pd[12 + 5 * b]; phv[b] = pd[13 + 5 * b];
        pcv[b] = pd[14 + 5 * b];
        axv[b] = ad[10 + 5 * b]; ayv[b] = ad[11 + 5 * b];
        awv[b] = ad[12 + 5 * b]; ahv[b] = ad[13 + 5 * b];
    }
    const bool obj = ad[14] > 0.0f;   // a's box-0 conf (channel 24)

    // ---- pairwise IoU, max over target boxes ----
    float miou[2];
#pragma unroll
    for (int pb = 0; pb < 2; ++pb) {
        const float p_tlx = pxv[pb] - 0.5f * pwv[pb];
        const float p_tly = pyv[pb] - 0.5f * phv[pb];
        const float p_brx = pxv[pb] + 0.5f * pwv[pb];
        const float p_bry = pyv[pb] + 0.5f * phv[pb];
        const float p_area = pwv[pb] * phv[pb];
        float best = -3.4e38f;
#pragma unroll
        for (int ab = 0; ab < 2; ++ab) {
            const float a_tlx = axv[ab] - 0.5f * awv[ab];
            const float a_tly = ayv[ab] - 0.5f * ahv[ab];
            const float a_brx = axv[ab] + 0.5f * awv[ab];
            const float a_bry = ayv[ab] + 0.5f * ahv[ab];
            float sx = fminf(p_brx, a_brx) - fmaxf(p_tlx, a_tlx);
            float sy = fminf(p_bry, a_bry) - fmaxf(p_tly, a_tly);
            sx = fmaxf(sx, 0.0f);
            sy = fmaxf(sy, 0.0f);
            const float inter = sx * sy;
            const float uni = p_area + awv[ab] * ahv[ab] - inter;
            const float iou = (uni == 0.0f) ? 0.0f : (inter / uni);  // where(zero,0)/where(zero,eps)
            best = fmaxf(best, iou);
        }
        miou[pb] = best;
    }
    // argmax over pred boxes, first-max tie-break (jnp.argmax semantics)
    const int resp = (miou[1] > miou[0]) ? 1 : 0;

    // ---- coordinate / confidence losses ----
#pragma unroll
    for (int b = 0; b < 2; ++b) {
        const bool oij = obj && (b == resp);
        if (oij) {
            const float dx = axv[b] - pxv[b];
            const float dy = ayv[b] - pyv[b];
            const float dw = sgnf(awv[b]) * sqrtf(awv[b] + EPSL) - sgnf(pwv[b]) * sqrtf(pwv[b] + EPSL);
            const float dh = sgnf(ahv[b]) * sqrtf(ahv[b] + EPSL) - sgnf(phv[b]) * sqrtf(phv[b] + EPSL);
            const float dc = 1.0f - pcv[b];  // (obj_ij^2 - obj_ij*pc)^2 with obj_ij==1
            lsum += 5.0f * (dx * dx + dy * dy + dw * dw + dh * dh) + dc * dc;
        } else {
            // noobj term: (noobj_ij*obj_ij - noobj_ij*pc)^2 = pc^2 when obj_ij==0
            lsum += 0.5f * pcv[b] * pcv[b];
        }
    }

    // ---- "class" loss over channels 10..29 (indices 0..19), gated by obj_i ----
    if (obj) {
#pragma unroll
        for (int k = 0; k < 20; ++k) {
            const float d = pd[k] - ad[k];
            lsum += d * d;
        }
    }
    return lsum;
}

__global__ __launch_bounds__(TPB) void yolo_loss_kernel(const float* __restrict__ p,
                                                        const float* __restrict__ a,
                                                        float* __restrict__ out,
                                                        long long n_cells) {
    __shared__ float lds[2][BUF_F];     // 61,440 B -> 2 blocks/CU
    __shared__ float wsum[TPB / 64];

    const int tid  = threadIdx.x;
    const int wid  = tid >> 6;
    const int lane = tid & 63;
    const long long FT = n_cells / TPB;   // full tiles (6272 at this shape)
    const int nb = gridDim.x;

    float lsum = 0.0f;
    long long t = blockIdx.x;
    int cur = 0;

    // prologue: stage first tile
    if (t < FT) stage_tile(p, a, lds[0], t, wid, lane);
    __syncthreads();   // vmcnt(0) drain: buf0 ready

    for (; t < FT; t += nb) {
        const long long tn = t + nb;
        if (tn < FT) stage_tile(p, a, lds[cur ^ 1], tn, wid, lane);  // prefetch next

        // consume current buffer
        float pd[20], ad[20];
        const float* bp = lds[cur] + tid * CH + 10;
        const float* ba = lds[cur] + TILE_F + tid * CH + 10;
#pragma unroll
        for (int i = 0; i < 10; ++i) {
            const float2 v = *(const float2*)(bp + 2 * i);
            pd[2 * i] = v.x; pd[2 * i + 1] = v.y;
        }
#pragma unroll
        for (int i = 0; i < 10; ++i) {
            const float2 v = *(const float2*)(ba + 2 * i);
            ad[2 * i] = v.x; ad[2 * i + 1] = v.y;
        }
        lsum += cell_loss(pd, ad);

        __syncthreads();   // drain prefetch (vmcnt0) + protect buf[cur] reads
        cur ^= 1;
    }

    // tail cells (n_cells % TPB; zero at this shape) -> block 0, direct loads
    if (blockIdx.x == 0) {
        const long long c = FT * TPB + tid;
        if (c < n_cells) {
            float pd[20], ad[20];
            const float2* cp2 = (const float2*)(p + c * CH + 10);
            const float2* ca2 = (const float2*)(a + c * CH + 10);
#pragma unroll
            for (int i = 0; i < 10; ++i) {
                const float2 v = cp2[i];
                pd[2 * i] = v.x; pd[2 * i + 1] = v.y;
            }
#pragma unroll
            for (int i = 0; i < 10; ++i) {
                const float2 v = ca2[i];
                ad[2 * i] = v.x; ad[2 * i + 1] = v.y;
            }
            lsum += cell_loss(pd, ad);
        }
    }

    // ---- reduction: wave shfl -> LDS -> one atomic per block ----
    float v = lsum;
#pragma unroll
    for (int off = 32; off > 0; off >>= 1)
        v += __shfl_down(v, off, 64);
    if ((tid & 63) == 0) wsum[tid >> 6] = v;
    __syncthreads();
    if (tid == 0) {
        float t2 = 0.0f;
#pragma unroll
        for (int w = 0; w < TPB / 64; ++w) t2 += wsum[w];
        atomicAdd(out, t2);
    }
}

extern "C" void kernel_launch(void* const* d_in, const int* in_sizes, int n_in,
                              void* d_out, int out_size, void* d_ws, size_t ws_size,
                              hipStream_t stream) {
    const float* p = (const float*)d_in[0];
    const float* a = (const float*)d_in[1];
    float* out = (float*)d_out;

    const long long n_cells = (long long)in_sizes[0] / CH;   // 16384*7*7 = 802816

    // d_out is re-poisoned (0xAA) before every timed replay -> must zero it here.
    hipMemsetAsync(d_out, 0, sizeof(float), stream);
    yolo_loss_kernel<<<GRID, TPB, 0, stream>>>(p, a, out, n_cells);
}